// Round 1
// baseline (266.796 us; speedup 1.0000x reference)
//
#include <hip/hip_runtime.h>

// Newton-Schulz batched inverse, 1024 x (128x128) fp32.
// One block per matrix; split-bf16 MFMA emulation of fp32 matmul.
// X' = 2X - X(WX); mm2 computed transposed so epilogue stores are packed.

#define NN 128
#define STR 136                 // LDS row stride in elements (272 B, 16B aligned)

typedef __attribute__((ext_vector_type(8))) short bf16x8;
typedef __attribute__((ext_vector_type(16))) float f32x16;
typedef __attribute__((ext_vector_type(4))) float f32x4;
typedef __attribute__((ext_vector_type(4))) unsigned short us4;

// LDS layout (bytes)
#define XRM_HI_OFF 0            // X row-major hi       128*136*2 = 34816
#define XRM_LO_OFF 34816        // X row-major lo
#define XCM_HI_OFF 69632        // X col-major hi
#define SCR_HI_OFF 104448       // T chunk col-major hi  64*136*2 = 17408
#define SCR_LO_OFF 121856       // T chunk col-major lo
#define RED_OFF    139264       // 256 floats: rowsums, colsums
#define LDS_BYTES  140288
// fp32 W staging (65536 B) aliases [0, 65536) = XRM region; dead after phase 0.

__device__ __forceinline__ unsigned short f2bf(float f) {
  unsigned u = __float_as_uint(f);
  unsigned r = (u + 0x7FFFu + ((u >> 16) & 1u)) >> 16;   // round-to-nearest-even
  return (unsigned short)r;
}
__device__ __forceinline__ float bf2f(unsigned short h) {
  return __uint_as_float(((unsigned)h) << 16);
}
__device__ __forceinline__ f32x16 zero16() {
  f32x16 z;
#pragma unroll
  for (int i = 0; i < 16; ++i) z[i] = 0.0f;
  return z;
}

__global__ void __launch_bounds__(256, 1)
ns_inverse_kernel(const float* __restrict__ Wglob, const int* __restrict__ nIt,
                  float* __restrict__ outglob) {
  extern __shared__ char lds[];
  unsigned short* xrm_hi = (unsigned short*)(lds + XRM_HI_OFF);
  unsigned short* xrm_lo = (unsigned short*)(lds + XRM_LO_OFF);
  unsigned short* xcm_hi = (unsigned short*)(lds + XCM_HI_OFF);
  unsigned short* scr_hi = (unsigned short*)(lds + SCR_HI_OFF);
  unsigned short* scr_lo = (unsigned short*)(lds + SCR_LO_OFF);
  float* red   = (float*)(lds + RED_OFF);
  float* stage = (float*)lds;

  const int b = blockIdx.x;
  const float* Wg = Wglob + (size_t)b * (NN * NN);
  float* outg = outglob + (size_t)b * (NN * NN);
  const int t = threadIdx.x;
  const int lane = t & 63;
  const int wv = t >> 6;          // wave 0..3, owns X rows [32wv, 32wv+32)
  const int l31 = lane & 31;
  const int half = lane >> 5;     // k-half for MFMA fragments
  const int niters = nIt[0];

  // ---------------- phase 0 ----------------
  {  // stage W fp32 into LDS (coalesced)
    const f32x4* src = (const f32x4*)Wg;
    f32x4* dst = (f32x4*)stage;
#pragma unroll
    for (int i = 0; i < 16; ++i) dst[t + 256 * i] = src[t + 256 * i];
  }
  __syncthreads();

  // norms: threads 0..127 row sums (rotated start: conflict-free), 128..255 col sums
  if (t < 128) {
    float s = 0.f;
    for (int jj = 0; jj < NN; ++jj) { int j = (jj + t) & 127; s += fabsf(stage[t * NN + j]); }
    red[t] = s;
  } else {
    int c = t - 128;
    float s = 0.f;
    for (int i = 0; i < NN; ++i) s += fabsf(stage[i * NN + c]);
    red[128 + c] = s;
  }
  __syncthreads();
  float ninf = 0.f, n1 = 0.f;
  for (int i = 0; i < 128; ++i) {          // broadcast reads, conflict-free
    ninf = fmaxf(ninf, red[i]);
    n1   = fmaxf(n1,   red[128 + i]);
  }
  const float scale = 1.0f / (n1 * ninf);

  // W A-fragments (hi bf16) for rows [32wv, 32wv+32): A[m=l31][k=16ks+8*half+j]
  bf16x8 wfrag[8];
  {
    const int am = 32 * wv + l31;
#pragma unroll
    for (int ks = 0; ks < 8; ++ks) {
      const float* p = stage + am * NN + ks * 16 + half * 8;
      f32x4 a = *(const f32x4*)p;
      f32x4 bq = *(const f32x4*)(p + 4);
      bf16x8 f;
      f[0] = (short)f2bf(a[0]);  f[1] = (short)f2bf(a[1]);
      f[2] = (short)f2bf(a[2]);  f[3] = (short)f2bf(a[3]);
      f[4] = (short)f2bf(bq[0]); f[5] = (short)f2bf(bq[1]);
      f[6] = (short)f2bf(bq[2]); f[7] = (short)f2bf(bq[3]);
      wfrag[ks] = f;
    }
  }
  __syncthreads();   // staging dead from here

  // X0 = W^T * scale -> xrm hi/lo + xcm hi (re-read W from global, L2-hot)
  {
    const int r = t >> 1;                 // X0 row (== own wave strip rows)
    const int kc = (t & 1) * 64;
#pragma unroll
    for (int j4 = 0; j4 < 16; ++j4) {
      us4 h4, l4;
#pragma unroll
      for (int i = 0; i < 4; ++i) {
        int j = j4 * 4 + i;
        float v = Wg[(size_t)(kc + j) * NN + r] * scale;
        unsigned short hh = f2bf(v);
        h4[i] = hh;
        l4[i] = f2bf(v - bf2f(hh));
        xcm_hi[(kc + j) * STR + r] = hh;
      }
      *(us4*)(xrm_hi + r * STR + kc + j4 * 4) = h4;
      *(us4*)(xrm_lo + r * STR + kc + j4 * 4) = l4;
    }
  }
  __syncthreads();

  // ---------------- iterations ----------------
  f32x16 acc[2][2];     // (X@T)^T tiles: [chunk c][tp]; rows 64c+32tp+, cols 32wv+
  for (int it = 0; it < niters; ++it) {
#pragma unroll
    for (int c = 0; c < 2; ++c)
#pragma unroll
      for (int tp = 0; tp < 2; ++tp) acc[c][tp] = zero16();

#pragma unroll
    for (int c = 0; c < 2; ++c) {
      // ---- mm1: T[32wv.., 64c..64c+64) = W_strip @ X  (hi-only operands) ----
      f32x16 tac0 = zero16(), tac1 = zero16();
#pragma unroll
      for (int ks = 0; ks < 8; ++ks) {
        int k0 = ks * 16 + half * 8;
        bf16x8 b0 = *(const bf16x8*)(xcm_hi + (64 * c + l31) * STR + k0);
        bf16x8 b1 = *(const bf16x8*)(xcm_hi + (64 * c + 32 + l31) * STR + k0);
        tac0 = __builtin_amdgcn_mfma_f32_32x32x16_bf16(wfrag[ks], b0, tac0, 0, 0, 0);
        tac1 = __builtin_amdgcn_mfma_f32_32x32x16_bf16(wfrag[ks], b1, tac1, 0, 0, 0);
      }
      // write T chunk to scratch, col-major, split hi/lo
#pragma unroll
      for (int tn = 0; tn < 2; ++tn) {
        const f32x16 ta = tn ? tac1 : tac0;
        unsigned short* sh = scr_hi + (32 * tn + l31) * STR + 32 * wv;
        unsigned short* sl = scr_lo + (32 * tn + l31) * STR + 32 * wv;
#pragma unroll
        for (int q = 0; q < 4; ++q) {
          int row0 = 8 * q + 4 * half;
          us4 h4, l4;
#pragma unroll
          for (int i = 0; i < 4; ++i) {
            float v = ta[4 * q + i];
            unsigned short hh = f2bf(v);
            h4[i] = hh;
            l4[i] = f2bf(v - bf2f(hh));
          }
          *(us4*)(sh + row0) = h4;
          *(us4*)(sl + row0) = l4;
        }
      }
      __syncthreads();

      // ---- mm2^T: acc += T^T @ X^T  (split x split, drop lo*lo) ----
#pragma unroll
      for (int ks = 0; ks < 8; ++ks) {
        int k0 = ks * 16 + half * 8;
        bf16x8 bh  = *(const bf16x8*)(xrm_hi + (32 * wv + l31) * STR + k0);
        bf16x8 bl  = *(const bf16x8*)(xrm_lo + (32 * wv + l31) * STR + k0);
        bf16x8 ah0 = *(const bf16x8*)(scr_hi + l31 * STR + k0);
        bf16x8 al0 = *(const bf16x8*)(scr_lo + l31 * STR + k0);
        bf16x8 ah1 = *(const bf16x8*)(scr_hi + (32 + l31) * STR + k0);
        bf16x8 al1 = *(const bf16x8*)(scr_lo + (32 + l31) * STR + k0);
        acc[c][0] = __builtin_amdgcn_mfma_f32_32x32x16_bf16(ah0, bh, acc[c][0], 0, 0, 0);
        acc[c][1] = __builtin_amdgcn_mfma_f32_32x32x16_bf16(ah1, bh, acc[c][1], 0, 0, 0);
        acc[c][0] = __builtin_amdgcn_mfma_f32_32x32x16_bf16(ah0, bl, acc[c][0], 0, 0, 0);
        acc[c][1] = __builtin_amdgcn_mfma_f32_32x32x16_bf16(ah1, bl, acc[c][1], 0, 0, 0);
        acc[c][0] = __builtin_amdgcn_mfma_f32_32x32x16_bf16(al0, bh, acc[c][0], 0, 0, 0);
        acc[c][1] = __builtin_amdgcn_mfma_f32_32x32x16_bf16(al1, bh, acc[c][1], 0, 0, 0);
      }
      __syncthreads();
    }

    // ---- epilogue: X' = 2X - (X@T); acc holds (X@T)^T ----
    const int pX = 32 * wv + l31;               // X' row (wave-owned)
    const bool last = (it == niters - 1);
#pragma unroll
    for (int c = 0; c < 2; ++c)
#pragma unroll
      for (int tp = 0; tp < 2; ++tp)
#pragma unroll
        for (int q = 0; q < 4; ++q) {
          int colX0 = 64 * c + 32 * tp + 8 * q + 4 * half;
          us4 xh4 = *(const us4*)(xrm_hi + pX * STR + colX0);
          us4 xl4 = *(const us4*)(xrm_lo + pX * STR + colX0);
          f32x4 v;
#pragma unroll
          for (int i = 0; i < 4; ++i)
            v[i] = 2.0f * (bf2f(xh4[i]) + bf2f(xl4[i])) - acc[c][tp][4 * q + i];
          if (last) {
            *(f32x4*)(outg + pX * NN + colX0) = v;
          } else {
            us4 h4, l4;
#pragma unroll
            for (int i = 0; i < 4; ++i) {
              unsigned short hh = f2bf(v[i]);
              h4[i] = hh;
              l4[i] = f2bf(v[i] - bf2f(hh));
              xcm_hi[(colX0 + i) * STR + pX] = hh;
            }
            *(us4*)(xrm_hi + pX * STR + colX0) = h4;
            *(us4*)(xrm_lo + pX * STR + colX0) = l4;
          }
        }
    __syncthreads();
  }
}

extern "C" void kernel_launch(void* const* d_in, const int* in_sizes, int n_in,
                              void* d_out, int out_size, void* d_ws, size_t ws_size,
                              hipStream_t stream) {
  const float* W = (const float*)d_in[0];
  const int* nIt = (const int*)d_in[1];
  float* out = (float*)d_out;
  const int nmat = in_sizes[0] / (NN * NN);   // 1024

  // Opt in to >64KB dynamic LDS (host-side, idempotent, capture-safe).
  hipFuncSetAttribute((const void*)ns_inverse_kernel,
                      hipFuncAttributeMaxDynamicSharedMemorySize, LDS_BYTES);
  ns_inverse_kernel<<<nmat, 256, LDS_BYTES, stream>>>(W, nIt, out);
}

// Round 2
// 225.030 us; speedup vs baseline: 1.1856x; 1.1856x over previous
//
#include <hip/hip_runtime.h>

// Newton-Schulz batched inverse, 1024 x (128x128) fp32.
// R2: 512 threads (8 waves, 2/SIMD), XOR-swizzled LDS (no pad, conflict-free),
// X-row fragments hoisted to registers, T scratch hi-only, 2 barriers/iter.

#define NN 128

typedef __attribute__((ext_vector_type(8))) short bf16x8;
typedef __attribute__((ext_vector_type(16))) float f32x16;
typedef __attribute__((ext_vector_type(4))) float f32x4;
typedef __attribute__((ext_vector_type(4))) unsigned short us4;

// LDS layout (bytes); all bf16 buffers are [128 x 128] with XOR-swizzled granules
#define XRM_HI_OFF 0        // X row-major hi    32768
#define XRM_LO_OFF 32768    // X row-major lo
#define XCM_HI_OFF 65536    // X col-major hi
#define SCR_HI_OFF 98304    // T  col-major hi
#define RED_OFF    131072   // 256 floats
#define LDS_BYTES  132096
// fp32 W staging (65536 B) aliases xrm_hi+xrm_lo; dead before X0 row-major fill.

__device__ __forceinline__ unsigned short f2bf(float f) {
  unsigned u = __float_as_uint(f);
  return (unsigned short)((u + 0x7FFFu + ((u >> 16) & 1u)) >> 16);  // RNE
}
__device__ __forceinline__ float bf2f(unsigned short h) {
  return __uint_as_float(((unsigned)h) << 16);
}
__device__ __forceinline__ f32x16 zero16() {
  f32x16 z;
#pragma unroll
  for (int i = 0; i < 16; ++i) z[i] = 0.0f;
  return z;
}
// Swizzled element offset in a [R][128] bf16 buffer: 8-elem granule g -> g ^ (R&7).
__device__ __forceinline__ int swz8(int R, int k0) {   // k0 % 8 == 0 (16B access)
  return R * 128 + (((k0 >> 3) ^ (R & 7)) << 3);
}
__device__ __forceinline__ int swz4(int R, int c0) {   // c0 % 4 == 0 (8B access)
  return R * 128 + ((((c0 >> 3) ^ (R & 7)) << 3) | (c0 & 7));
}
__device__ __forceinline__ int swz1(int R, int c) {    // scalar
  return R * 128 + ((((c >> 3) ^ (R & 7)) << 3) | (c & 7));
}

__global__ void __launch_bounds__(512, 1)
ns_inverse_kernel(const float* __restrict__ Wglob, const int* __restrict__ nIt,
                  float* __restrict__ outglob) {
  extern __shared__ char lds[];
  unsigned short* xrm_hi = (unsigned short*)(lds + XRM_HI_OFF);
  unsigned short* xrm_lo = (unsigned short*)(lds + XRM_LO_OFF);
  unsigned short* xcm_hi = (unsigned short*)(lds + XCM_HI_OFF);
  unsigned short* scr_hi = (unsigned short*)(lds + SCR_HI_OFF);
  float* red   = (float*)(lds + RED_OFF);
  float* stage = (float*)lds;

  const int b = blockIdx.x;
  const float* Wg = Wglob + (size_t)b * (NN * NN);
  float* outg = outglob + (size_t)b * (NN * NN);
  const int t = threadIdx.x;      // 0..511
  const int lane = t & 63;
  const int wv = t >> 6;          // 0..7
  const int l31 = lane & 31;
  const int half = lane >> 5;
  const int s = wv & 3;           // 32-row strip: W rows (mm1 A), X rows (mm2 B, X' rows)
  const int u = wv >> 2;          // 64-wide half: T cols (mm1), X' cols (mm2/epilogue)
  const int niters = nIt[0];

  // ---- phase 0: stage W fp32 into LDS (coalesced) ----
  {
    const f32x4* src = (const f32x4*)Wg;
    f32x4* dst = (f32x4*)stage;
#pragma unroll
    for (int i = 0; i < 8; ++i) dst[t + 512 * i] = src[t + 512 * i];
  }
  __syncthreads();

  // ---- norms ----
  if (t < 128) {            // row sums (rotated start: conflict-free)
    float ssum = 0.f;
    for (int jj = 0; jj < NN; ++jj) { int j = (jj + t) & 127; ssum += fabsf(stage[t * NN + j]); }
    red[t] = ssum;
  } else if (t < 256) {     // col sums
    int c = t - 128;
    float ssum = 0.f;
    for (int i = 0; i < NN; ++i) ssum += fabsf(stage[i * NN + c]);
    red[128 + c] = ssum;
  }
  __syncthreads();
  float ninf = 0.f, n1 = 0.f;
  for (int i = 0; i < 128; ++i) {   // broadcast reads
    ninf = fmaxf(ninf, red[i]);
    n1   = fmaxf(n1,   red[128 + i]);
  }
  const float scale = 1.0f / (n1 * ninf);

  // ---- wfrag: W rows [32s, 32s+32) hi-bf16 A-fragments (from stage) ----
  bf16x8 wfrag[8];
  {
    const int am = 32 * s + l31;
#pragma unroll
    for (int ks = 0; ks < 8; ++ks) {
      const float* p = stage + am * NN + ks * 16 + half * 8;
      f32x4 a = *(const f32x4*)p;
      f32x4 bq = *(const f32x4*)(p + 4);
      bf16x8 f;
      f[0] = (short)f2bf(a[0]);  f[1] = (short)f2bf(a[1]);
      f[2] = (short)f2bf(a[2]);  f[3] = (short)f2bf(a[3]);
      f[4] = (short)f2bf(bq[0]); f[5] = (short)f2bf(bq[1]);
      f[6] = (short)f2bf(bq[2]); f[7] = (short)f2bf(bq[3]);
      wfrag[ks] = f;
    }
  }

  // ---- X0 col-major: xcm[c][k] = W[c][k]*scale (straight scaled copy from stage) ----
#pragma unroll
  for (int i = 0; i < 8; ++i) {
    int e0 = (t + 512 * i) * 4;     // flat element index
    int R = e0 >> 7, c0 = e0 & 127;
    f32x4 v = *(const f32x4*)(stage + e0);
    us4 h4;
#pragma unroll
    for (int j = 0; j < 4; ++j) h4[j] = f2bf(v[j] * scale);
    *(us4*)(xcm_hi + swz4(R, c0)) = h4;
  }
  __syncthreads();   // stage dead from here (xrm fill overwrites it)

  // ---- X0 row-major hi+lo: transpose-read W from global (L2-hot) ----
  {
    const int r = t & 127;
    const int kc = (t >> 7) * 32;
#pragma unroll
    for (int j4 = 0; j4 < 8; ++j4) {
      int c0 = kc + j4 * 4;
      us4 h4, l4;
#pragma unroll
      for (int i = 0; i < 4; ++i) {
        float v = Wg[(size_t)(c0 + i) * NN + r] * scale;
        unsigned short hh = f2bf(v);
        h4[i] = hh;
        l4[i] = f2bf(v - bf2f(hh));
      }
      int off = swz4(r, c0);
      *(us4*)(xrm_hi + off) = h4;
      *(us4*)(xrm_lo + off) = l4;
    }
  }
  __syncthreads();

  // ---------------- iterations: X' = 2X - X(WX) ----------------
  for (int it = 0; it < niters; ++it) {
    // xfrag: X rows [32s+l31] hi+lo B-fragments (own strip + cross-u barrier-protected)
    bf16x8 xh[8], xl[8];
    {
      const int xr = 32 * s + l31;
#pragma unroll
      for (int ks = 0; ks < 8; ++ks) {
        int off = swz8(xr, ks * 16 + half * 8);
        xh[ks] = *(const bf16x8*)(xrm_hi + off);
        xl[ks] = *(const bf16x8*)(xrm_lo + off);
      }
    }

    // ---- mm1: T[32s.., 64u..64u+64) = W_strip @ X (hi-only) ----
    f32x16 t0 = zero16(), t1 = zero16();
#pragma unroll
    for (int ks = 0; ks < 8; ++ks) {
      int k0 = ks * 16 + half * 8;
      bf16x8 b0 = *(const bf16x8*)(xcm_hi + swz8(64 * u + l31, k0));
      bf16x8 b1 = *(const bf16x8*)(xcm_hi + swz8(64 * u + 32 + l31, k0));
      t0 = __builtin_amdgcn_mfma_f32_32x32x16_bf16(wfrag[ks], b0, t0, 0, 0, 0);
      t1 = __builtin_amdgcn_mfma_f32_32x32x16_bf16(wfrag[ks], b1, t1, 0, 0, 0);
    }
    // write T tiles to scr (col-major, hi only)
#pragma unroll
    for (int tn = 0; tn < 2; ++tn) {
      const f32x16 ta = tn ? t1 : t0;
      const int tcol = 64 * u + 32 * tn + l31;
#pragma unroll
      for (int q = 0; q < 4; ++q) {
        int row0 = 32 * s + 8 * q + 4 * half;
        us4 h4;
#pragma unroll
        for (int i = 0; i < 4; ++i) h4[i] = f2bf(ta[4 * q + i]);
        *(us4*)(scr_hi + swz4(tcol, row0)) = h4;
      }
    }
    __syncthreads();   // barrier 1: full T ready

    // ---- mm2^T: acc = T^T @ X^T; rows [64u+32tp), cols [32s) ----
    f32x16 a0 = zero16(), a1 = zero16();
#pragma unroll
    for (int ks = 0; ks < 8; ++ks) {
      int k0 = ks * 16 + half * 8;
      bf16x8 ah0 = *(const bf16x8*)(scr_hi + swz8(64 * u + l31, k0));
      bf16x8 ah1 = *(const bf16x8*)(scr_hi + swz8(64 * u + 32 + l31, k0));
      a0 = __builtin_amdgcn_mfma_f32_32x32x16_bf16(ah0, xh[ks], a0, 0, 0, 0);
      a1 = __builtin_amdgcn_mfma_f32_32x32x16_bf16(ah1, xh[ks], a1, 0, 0, 0);
      a0 = __builtin_amdgcn_mfma_f32_32x32x16_bf16(ah0, xl[ks], a0, 0, 0, 0);
      a1 = __builtin_amdgcn_mfma_f32_32x32x16_bf16(ah1, xl[ks], a1, 0, 0, 0);
    }

    // ---- epilogue: X' = 2X - (X@T); acc holds (X@T)^T ----
    const int pX = 32 * s + l31;
    const bool last = (it == niters - 1);
#pragma unroll
    for (int tp = 0; tp < 2; ++tp) {
      const f32x16 ac = tp ? a1 : a0;
#pragma unroll
      for (int q = 0; q < 4; ++q) {
        int c0 = 64 * u + 32 * tp + 8 * q + 4 * half;
        int offr = swz4(pX, c0);
        us4 xh4 = *(const us4*)(xrm_hi + offr);
        us4 xl4 = *(const us4*)(xrm_lo + offr);
        f32x4 v;
#pragma unroll
        for (int i = 0; i < 4; ++i)
          v[i] = 2.0f * (bf2f(xh4[i]) + bf2f(xl4[i])) - ac[4 * q + i];
        if (last) {
          *(f32x4*)(outg + pX * NN + c0) = v;
        } else {
          us4 h4, l4;
#pragma unroll
          for (int i = 0; i < 4; ++i) {
            unsigned short hh = f2bf(v[i]);
            h4[i] = hh;
            l4[i] = f2bf(v[i] - bf2f(hh));
            xcm_hi[swz1(c0 + i, pX)] = hh;
          }
          *(us4*)(xrm_hi + offr) = h4;
          *(us4*)(xrm_lo + offr) = l4;
        }
      }
    }
    __syncthreads();   // barrier 2: X' committed
  }
}

extern "C" void kernel_launch(void* const* d_in, const int* in_sizes, int n_in,
                              void* d_out, int out_size, void* d_ws, size_t ws_size,
                              hipStream_t stream) {
  const float* W = (const float*)d_in[0];
  const int* nIt = (const int*)d_in[1];
  float* out = (float*)d_out;
  const int nmat = in_sizes[0] / (NN * NN);   // 1024

  hipFuncSetAttribute((const void*)ns_inverse_kernel,
                      hipFuncAttributeMaxDynamicSharedMemorySize, LDS_BYTES);
  ns_inverse_kernel<<<nmat, 512, LDS_BYTES, stream>>>(W, nIt, out);
}

// Round 3
// 223.429 us; speedup vs baseline: 1.1941x; 1.0072x over previous
//
#include <hip/hip_runtime.h>

// Newton-Schulz batched inverse, 1024 x (128x128) fp32.
// R3: hi-only bf16 X everywhere (2d0-d1-d2 cancellation), 65KB LDS -> 2 blocks/CU,
// T chunks alias consumed xcm halves, XOR-swizzled conflict-free layout.

#define NN 128

typedef __attribute__((ext_vector_type(8))) short bf16x8;
typedef __attribute__((ext_vector_type(16))) float f32x16;
typedef __attribute__((ext_vector_type(4))) float f32x4;
typedef __attribute__((ext_vector_type(4))) unsigned short us4;

// LDS (bytes): xrm [0,32768) row-major X hi; xcm [32768,65536) col-major X hi
// (T^T chunk c overwrites xcm rows [64c,64c+64) after they're consumed);
// red [65536,66560); fp32 W stage (64K) aliases [0,65536), dead before fills.
#define XRM_OFF 0
#define XCM_OFF 32768
#define RED_OFF 65536
#define LDS_BYTES 66560

__device__ __forceinline__ unsigned short f2bf(float f) {
  unsigned u = __float_as_uint(f);
  return (unsigned short)((u + 0x7FFFu + ((u >> 16) & 1u)) >> 16);  // RNE
}
__device__ __forceinline__ float bf2f(unsigned short h) {
  return __uint_as_float(((unsigned)h) << 16);
}
__device__ __forceinline__ f32x16 zero16() {
  f32x16 z;
#pragma unroll
  for (int i = 0; i < 16; ++i) z[i] = 0.0f;
  return z;
}
// XOR swizzle in a [R][128] bf16 buffer: 8-elem granule g -> g ^ (R&7).
__device__ __forceinline__ int swz8(int R, int k0) {  // k0 % 8 == 0
  return R * 128 + (((k0 >> 3) ^ (R & 7)) << 3);
}
__device__ __forceinline__ int swz4(int R, int c0) {  // c0 % 4 == 0
  return R * 128 + ((((c0 >> 3) ^ (R & 7)) << 3) | (c0 & 7));
}
__device__ __forceinline__ int swz1(int R, int c) {
  return R * 128 + ((((c >> 3) ^ (R & 7)) << 3) | (c & 7));
}

__global__ void __launch_bounds__(512, 4)
ns_inverse_kernel(const float* __restrict__ Wglob, const int* __restrict__ nIt,
                  float* __restrict__ outglob) {
  extern __shared__ char lds[];
  unsigned short* xrm = (unsigned short*)(lds + XRM_OFF);
  unsigned short* xcm = (unsigned short*)(lds + XCM_OFF);
  float* red   = (float*)(lds + RED_OFF);
  float* stage = (float*)lds;

  const int b = blockIdx.x;
  const float* Wg = Wglob + (size_t)b * (NN * NN);
  float* outg = outglob + (size_t)b * (NN * NN);
  const int t = threadIdx.x;      // 0..511
  const int lane = t & 63;
  const int wv = t >> 6;          // 0..7
  const int l31 = lane & 31;
  const int half = lane >> 5;
  const int s = wv & 3;           // strip: W rows / X' rows
  const int u = wv >> 2;          // 32-col band within T chunk
  const int niters = nIt[0];

  // ---- phase 0: stage W fp32 into LDS ----
  {
    const f32x4* src = (const f32x4*)Wg;
    f32x4* dst = (f32x4*)stage;
#pragma unroll
    for (int i = 0; i < 8; ++i) dst[t + 512 * i] = src[t + 512 * i];
  }
  __syncthreads();

  // ---- norms ----
  if (t < 128) {            // row sums (rotated start)
    float ssum = 0.f;
    for (int jj = 0; jj < NN; ++jj) { int j = (jj + t) & 127; ssum += fabsf(stage[t * NN + j]); }
    red[t] = ssum;
  } else if (t < 256) {     // col sums
    int c = t - 128;
    float ssum = 0.f;
    for (int i = 0; i < NN; ++i) ssum += fabsf(stage[i * NN + c]);
    red[128 + c] = ssum;
  }
  __syncthreads();
  float ninf = 0.f, n1 = 0.f;
  for (int i = 0; i < 128; ++i) {
    ninf = fmaxf(ninf, red[i]);
    n1   = fmaxf(n1,   red[128 + i]);
  }
  const float scale = 1.0f / (n1 * ninf);

  // ---- wfrag: W strip-s rows as hi-bf16 A-fragments ----
  bf16x8 wfrag[8];
  {
    const int am = 32 * s + l31;
#pragma unroll
    for (int ks = 0; ks < 8; ++ks) {
      const float* p = stage + am * NN + ks * 16 + half * 8;
      f32x4 a = *(const f32x4*)p;
      f32x4 bq = *(const f32x4*)(p + 4);
      bf16x8 f;
      f[0] = (short)f2bf(a[0]);  f[1] = (short)f2bf(a[1]);
      f[2] = (short)f2bf(a[2]);  f[3] = (short)f2bf(a[3]);
      f[4] = (short)f2bf(bq[0]); f[5] = (short)f2bf(bq[1]);
      f[6] = (short)f2bf(bq[2]); f[7] = (short)f2bf(bq[3]);
      wfrag[ks] = f;
    }
  }
  __syncthreads();   // stage fully dead

  // ---- X0 fills from global (L2/L3-hot). X0 = W^T * scale ----
  // xcm row n = X0 col n = W row n (coalesced read)
#pragma unroll
  for (int i = 0; i < 8; ++i) {
    int e0 = (t + 512 * i) * 4;
    int R = e0 >> 7, c0 = e0 & 127;
    f32x4 v = *(const f32x4*)(Wg + e0);
    us4 h4;
#pragma unroll
    for (int j = 0; j < 4; ++j) h4[j] = f2bf(v[j] * scale);
    *(us4*)(xcm + swz4(R, c0)) = h4;
  }
  // xrm row r = X0 row r = W col r (transpose read)
  {
    const int r = t & 127;
    const int kc = (t >> 7) * 32;
#pragma unroll
    for (int j4 = 0; j4 < 8; ++j4) {
      int c0 = kc + j4 * 4;
      us4 h4;
#pragma unroll
      for (int i = 0; i < 4; ++i) h4[i] = f2bf(Wg[(size_t)(c0 + i) * NN + r] * scale);
      *(us4*)(xrm + swz4(r, c0)) = h4;
    }
  }
  __syncthreads();

  // ---------------- iterations: X' = 2X - X(WX) ----------------
  const int pX = 32 * s + l31;          // lane-owned X row
  const int rr = 32 * u + l31;          // lane-owned T col (within chunk)
  for (int it = 0; it < niters; ++it) {
    const bool last = (it == niters - 1);

    // X-row hi fragments (mm2 B operand, constant across chunks)
    bf16x8 xh[8];
#pragma unroll
    for (int ks = 0; ks < 8; ++ks)
      xh[ks] = *(const bf16x8*)(xrm + swz8(pX, ks * 16 + half * 8));

    // mm1 c0: T[:, rr] for T cols [0,64)
    f32x16 t0 = zero16();
#pragma unroll
    for (int ks = 0; ks < 8; ++ks) {
      bf16x8 bv = *(const bf16x8*)(xcm + swz8(rr, ks * 16 + half * 8));
      t0 = __builtin_amdgcn_mfma_f32_32x32x16_bf16(wfrag[ks], bv, t0, 0, 0, 0);
    }
    __syncthreads();   // B1: xcm rows [0,64) consumed by all waves

    // write T^T c0 into scrA = xcm rows [0,64)
    {
      unsigned short* scrA = xcm;
#pragma unroll
      for (int q = 0; q < 4; ++q) {
        us4 h4;
#pragma unroll
        for (int i = 0; i < 4; ++i) h4[i] = f2bf(t0[4 * q + i]);
        *(us4*)(scrA + swz4(rr, 32 * s + 8 * q + 4 * half)) = h4;
      }
    }
    // mm1 c1: reads xcm rows [64,128) (disjoint from scrA writes)
    f32x16 t1 = zero16();
#pragma unroll
    for (int ks = 0; ks < 8; ++ks) {
      bf16x8 bv = *(const bf16x8*)(xcm + swz8(64 + rr, ks * 16 + half * 8));
      t1 = __builtin_amdgcn_mfma_f32_32x32x16_bf16(wfrag[ks], bv, t1, 0, 0, 0);
    }
    __syncthreads();   // B2: scrA visible; xcm rows [64,128) consumed

    // write T^T c1 into scrB = xcm rows [64,128)
    {
      unsigned short* scrB = xcm + 64 * 128;
#pragma unroll
      for (int q = 0; q < 4; ++q) {
        us4 h4;
#pragma unroll
        for (int i = 0; i < 4; ++i) h4[i] = f2bf(t1[4 * q + i]);
        *(us4*)(scrB + swz4(rr, 32 * s + 8 * q + 4 * half)) = h4;
      }
    }
    // mm2 c0: acc0 = (X@T)^T rows [32u,32u+32), cols strip s
    f32x16 acc0 = zero16();
#pragma unroll
    for (int ks = 0; ks < 8; ++ks) {
      bf16x8 av = *(const bf16x8*)(xcm + swz8(rr, ks * 16 + half * 8));  // scrA
      acc0 = __builtin_amdgcn_mfma_f32_32x32x16_bf16(av, xh[ks], acc0, 0, 0, 0);
    }
    __syncthreads();   // B3: scrB visible

    // mm2 c1
    f32x16 acc1 = zero16();
#pragma unroll
    for (int ks = 0; ks < 8; ++ks) {
      bf16x8 av = *(const bf16x8*)(xcm + 64 * 128 + swz8(rr, ks * 16 + half * 8));  // scrB
      acc1 = __builtin_amdgcn_mfma_f32_32x32x16_bf16(av, xh[ks], acc1, 0, 0, 0);
    }
    __syncthreads();   // B4: all scr reads done before xcm overwrite

    // epilogue: X'[pX][64c+32u+m] = 2*X - (X@T); acc holds (X@T)^T
#pragma unroll
    for (int c = 0; c < 2; ++c) {
      const f32x16 ac = c ? acc1 : acc0;
#pragma unroll
      for (int q = 0; q < 4; ++q) {
        int c0m = 64 * c + 32 * u + 8 * q + 4 * half;
        int offr = swz4(pX, c0m);
        us4 xh4 = *(const us4*)(xrm + offr);
        f32x4 v;
#pragma unroll
        for (int i = 0; i < 4; ++i)
          v[i] = 2.0f * bf2f(xh4[i]) - ac[4 * q + i];
        if (last) {
          *(f32x4*)(outg + pX * NN + c0m) = v;
        } else {
          us4 h4;
#pragma unroll
          for (int i = 0; i < 4; ++i) {
            unsigned short hh = f2bf(v[i]);
            h4[i] = hh;
            xcm[swz1(c0m + i, pX)] = hh;
          }
          *(us4*)(xrm + offr) = h4;
        }
      }
    }
    __syncthreads();   // B5: X' committed
  }
}

extern "C" void kernel_launch(void* const* d_in, const int* in_sizes, int n_in,
                              void* d_out, int out_size, void* d_ws, size_t ws_size,
                              hipStream_t stream) {
  const float* W = (const float*)d_in[0];
  const int* nIt = (const int*)d_in[1];
  float* out = (float*)d_out;
  const int nmat = in_sizes[0] / (NN * NN);   // 1024

  hipFuncSetAttribute((const void*)ns_inverse_kernel,
                      hipFuncAttributeMaxDynamicSharedMemorySize, LDS_BYTES);
  ns_inverse_kernel<<<nmat, 512, LDS_BYTES, stream>>>(W, nIt, out);
}

// Round 4
// 208.203 us; speedup vs baseline: 1.2814x; 1.0731x over previous
//
#include <hip/hip_runtime.h>

// Newton-Schulz batched inverse, 1024 x (128x128) fp32.
// R4: fix R3's register spill (172MB scratch writes). No xh register array --
// mm2 reads B-fragments straight from LDS; accumulators tightly scoped.
// hi-only bf16 X (2d0-d1-d2 cancellation), 65KB LDS -> 2 blocks/CU.

#define NN 128

typedef __attribute__((ext_vector_type(8))) short bf16x8;
typedef __attribute__((ext_vector_type(16))) float f32x16;
typedef __attribute__((ext_vector_type(4))) float f32x4;
typedef __attribute__((ext_vector_type(4))) unsigned short us4;

// LDS (bytes): xrm [0,32768) row-major X hi; xcm [32768,65536) col-major X hi
// (T^T chunk c overwrites xcm rows [64c,64c+64) after they're consumed);
// red [65536,66560); fp32 W stage (64K) aliases [0,65536), dead before fills.
#define XRM_OFF 0
#define XCM_OFF 32768
#define RED_OFF 65536
#define LDS_BYTES 66560

__device__ __forceinline__ unsigned short f2bf(float f) {
  unsigned u = __float_as_uint(f);
  return (unsigned short)((u + 0x7FFFu + ((u >> 16) & 1u)) >> 16);  // RNE
}
__device__ __forceinline__ float bf2f(unsigned short h) {
  return __uint_as_float(((unsigned)h) << 16);
}
__device__ __forceinline__ f32x16 zero16() {
  f32x16 z;
#pragma unroll
  for (int i = 0; i < 16; ++i) z[i] = 0.0f;
  return z;
}
// XOR swizzle in a [R][128] bf16 buffer: 8-elem granule g -> g ^ (R&7).
__device__ __forceinline__ int swz8(int R, int k0) {  // k0 % 8 == 0
  return R * 128 + (((k0 >> 3) ^ (R & 7)) << 3);
}
__device__ __forceinline__ int swz4(int R, int c0) {  // c0 % 4 == 0
  return R * 128 + ((((c0 >> 3) ^ (R & 7)) << 3) | (c0 & 7));
}
__device__ __forceinline__ int swz1(int R, int c) {
  return R * 128 + ((((c >> 3) ^ (R & 7)) << 3) | (c & 7));
}

__global__ void __launch_bounds__(512, 4)
ns_inverse_kernel(const float* __restrict__ Wglob, const int* __restrict__ nIt,
                  float* __restrict__ outglob) {
  extern __shared__ char lds[];
  unsigned short* xrm = (unsigned short*)(lds + XRM_OFF);
  unsigned short* xcm = (unsigned short*)(lds + XCM_OFF);
  float* red   = (float*)(lds + RED_OFF);
  float* stage = (float*)lds;

  const int b = blockIdx.x;
  const float* Wg = Wglob + (size_t)b * (NN * NN);
  float* outg = outglob + (size_t)b * (NN * NN);
  const int t = threadIdx.x;      // 0..511
  const int lane = t & 63;
  const int wv = t >> 6;          // 0..7
  const int l31 = lane & 31;
  const int half = lane >> 5;
  const int s = wv & 3;           // strip: W rows / X' rows
  const int u = wv >> 2;          // 32-col band within T chunk
  const int niters = nIt[0];

  // ---- phase 0: stage W fp32 into LDS ----
  {
    const f32x4* src = (const f32x4*)Wg;
    f32x4* dst = (f32x4*)stage;
#pragma unroll
    for (int i = 0; i < 8; ++i) dst[t + 512 * i] = src[t + 512 * i];
  }
  __syncthreads();

  // ---- norms ----
  if (t < 128) {            // row sums (rotated start)
    float ssum = 0.f;
    for (int jj = 0; jj < NN; ++jj) { int j = (jj + t) & 127; ssum += fabsf(stage[t * NN + j]); }
    red[t] = ssum;
  } else if (t < 256) {     // col sums
    int c = t - 128;
    float ssum = 0.f;
    for (int i = 0; i < NN; ++i) ssum += fabsf(stage[i * NN + c]);
    red[128 + c] = ssum;
  }
  __syncthreads();
  float ninf = 0.f, n1 = 0.f;
  for (int i = 0; i < 128; ++i) {
    ninf = fmaxf(ninf, red[i]);
    n1   = fmaxf(n1,   red[128 + i]);
  }
  const float scale = 1.0f / (n1 * ninf);

  // ---- wfrag: W strip-s rows as hi-bf16 A-fragments ----
  bf16x8 wfrag[8];
  {
    const int am = 32 * s + l31;
#pragma unroll
    for (int ks = 0; ks < 8; ++ks) {
      const float* p = stage + am * NN + ks * 16 + half * 8;
      f32x4 a = *(const f32x4*)p;
      f32x4 bq = *(const f32x4*)(p + 4);
      bf16x8 f;
      f[0] = (short)f2bf(a[0]);  f[1] = (short)f2bf(a[1]);
      f[2] = (short)f2bf(a[2]);  f[3] = (short)f2bf(a[3]);
      f[4] = (short)f2bf(bq[0]); f[5] = (short)f2bf(bq[1]);
      f[6] = (short)f2bf(bq[2]); f[7] = (short)f2bf(bq[3]);
      wfrag[ks] = f;
    }
  }
  __syncthreads();   // stage fully dead

  // ---- X0 fills from global (L2-hot). X0 = W^T * scale ----
  // xcm row n = X0 col n = W row n (coalesced read)
#pragma unroll
  for (int i = 0; i < 8; ++i) {
    int e0 = (t + 512 * i) * 4;
    int R = e0 >> 7, c0 = e0 & 127;
    f32x4 v = *(const f32x4*)(Wg + e0);
    us4 h4;
#pragma unroll
    for (int j = 0; j < 4; ++j) h4[j] = f2bf(v[j] * scale);
    *(us4*)(xcm + swz4(R, c0)) = h4;
  }
  // xrm row r = X0 row r = W col r (transpose read)
  {
    const int r = t & 127;
    const int kc = (t >> 7) * 32;
#pragma unroll
    for (int j4 = 0; j4 < 8; ++j4) {
      int c0 = kc + j4 * 4;
      us4 h4;
#pragma unroll
      for (int i = 0; i < 4; ++i) h4[i] = f2bf(Wg[(size_t)(c0 + i) * NN + r] * scale);
      *(us4*)(xrm + swz4(r, c0)) = h4;
    }
  }
  __syncthreads();

  // ---------------- iterations: X' = 2X - X(WX) ----------------
  const int pX = 32 * s + l31;          // lane-owned X row
  const int rr = 32 * u + l31;          // lane-owned T col (within chunk)
  for (int it = 0; it < niters; ++it) {
    const bool last = (it == niters - 1);

    // ---- mm1 c0: T cols [0,64) = W_strip @ X[:, 0:64] ----
    {
      f32x16 t0 = zero16();
#pragma unroll
      for (int ks = 0; ks < 8; ++ks) {
        bf16x8 bv = *(const bf16x8*)(xcm + swz8(rr, ks * 16 + half * 8));
        t0 = __builtin_amdgcn_mfma_f32_32x32x16_bf16(wfrag[ks], bv, t0, 0, 0, 0);
      }
      __syncthreads();   // B1: xcm rows [0,64) consumed by all waves
      // write T^T c0 into scrA = xcm rows [0,64)
#pragma unroll
      for (int q = 0; q < 4; ++q) {
        us4 h4;
#pragma unroll
        for (int i = 0; i < 4; ++i) h4[i] = f2bf(t0[4 * q + i]);
        *(us4*)(xcm + swz4(rr, 32 * s + 8 * q + 4 * half)) = h4;
      }
    }
    // ---- mm1 c1: reads xcm rows [64,128) (disjoint from scrA writes) ----
    {
      f32x16 t1 = zero16();
#pragma unroll
      for (int ks = 0; ks < 8; ++ks) {
        bf16x8 bv = *(const bf16x8*)(xcm + swz8(64 + rr, ks * 16 + half * 8));
        t1 = __builtin_amdgcn_mfma_f32_32x32x16_bf16(wfrag[ks], bv, t1, 0, 0, 0);
      }
      __syncthreads();   // B2: scrA visible; xcm rows [64,128) consumed
      // write T^T c1 into scrB = xcm rows [64,128)
#pragma unroll
      for (int q = 0; q < 4; ++q) {
        us4 h4;
#pragma unroll
        for (int i = 0; i < 4; ++i) h4[i] = f2bf(t1[4 * q + i]);
        *(us4*)(xcm + 64 * 128 + swz4(rr, 32 * s + 8 * q + 4 * half)) = h4;
      }
    }

    // ---- mm2 c0: acc0 = (X@T)^T rows [32u+), cols strip s (B from LDS) ----
    f32x16 acc0 = zero16();
#pragma unroll
    for (int ks = 0; ks < 8; ++ks) {
      int k0 = ks * 16 + half * 8;
      bf16x8 av = *(const bf16x8*)(xcm + swz8(rr, k0));          // scrA
      bf16x8 bv = *(const bf16x8*)(xrm + swz8(pX, k0));          // X row frag
      acc0 = __builtin_amdgcn_mfma_f32_32x32x16_bf16(av, bv, acc0, 0, 0, 0);
    }
    __syncthreads();   // B3: scrB visible

    // ---- mm2 c1 ----
    f32x16 acc1 = zero16();
#pragma unroll
    for (int ks = 0; ks < 8; ++ks) {
      int k0 = ks * 16 + half * 8;
      bf16x8 av = *(const bf16x8*)(xcm + 64 * 128 + swz8(rr, k0));  // scrB
      bf16x8 bv = *(const bf16x8*)(xrm + swz8(pX, k0));
      acc1 = __builtin_amdgcn_mfma_f32_32x32x16_bf16(av, bv, acc1, 0, 0, 0);
    }
    __syncthreads();   // B4: all scr/xrm reads done before overwrite

    // ---- epilogue: X' = 2X - (X@T); acc holds (X@T)^T ----
#pragma unroll
    for (int c = 0; c < 2; ++c) {
      const f32x16 ac = c ? acc1 : acc0;
#pragma unroll
      for (int q = 0; q < 4; ++q) {
        int c0m = 64 * c + 32 * u + 8 * q + 4 * half;
        int offr = swz4(pX, c0m);
        us4 xh4 = *(const us4*)(xrm + offr);
        f32x4 v;
#pragma unroll
        for (int i = 0; i < 4; ++i)
          v[i] = 2.0f * bf2f(xh4[i]) - ac[4 * q + i];
        if (last) {
          *(f32x4*)(outg + pX * NN + c0m) = v;
        } else {
          us4 h4;
#pragma unroll
          for (int i = 0; i < 4; ++i) {
            unsigned short hh = f2bf(v[i]);
            h4[i] = hh;
            xcm[swz1(c0m + i, pX)] = hh;
          }
          *(us4*)(xrm + offr) = h4;
        }
      }
    }
    __syncthreads();   // B5: X' committed
  }
}

extern "C" void kernel_launch(void* const* d_in, const int* in_sizes, int n_in,
                              void* d_out, int out_size, void* d_ws, size_t ws_size,
                              hipStream_t stream) {
  const float* W = (const float*)d_in[0];
  const int* nIt = (const int*)d_in[1];
  float* out = (float*)d_out;
  const int nmat = in_sizes[0] / (NN * NN);   // 1024

  hipFuncSetAttribute((const void*)ns_inverse_kernel,
                      hipFuncAttributeMaxDynamicSharedMemorySize, LDS_BYTES);
  ns_inverse_kernel<<<nmat, 512, LDS_BYTES, stream>>>(W, nIt, out);
}